// Round 7
// baseline (158.268 us; speedup 1.0000x reference)
//
#include <hip/hip_runtime.h>
#include <hip/hip_bf16.h>
#include <stdint.h>

typedef __attribute__((ext_vector_type(4))) int i32x4;

static constexpr long M_ = 16384;   // 4*4096 rows of x
static constexpr long N_ = 2048;    // out_features
static constexpr long K_ = 2048;    // in_features

// ---- 128x256 i8 GEMM, 2 phases per K-step, 2 blocks/CU ----
// 4 waves (1m x 4n), 256 threads, per-wave output 128x64, BK=64 i8.
// LDS 48 KB: A[2][128][64] (2x8KB) + B[2][256][64] (2x16KB) -> two blocks
// co-resident per CU (96 KB LDS, 8 waves = 2/SIMD at ~232 unified regs).
// Cross-block overlap is the mechanism: block X's LDS window hides under
// block Y's MFMA window (same-block waves are barrier-locked and can't).
// Swizzle: row r, logical 16B-chunk c stored at physical chunk c ^ ((r>>1)&3).

#define GLOAD_LDS16(g, l)                                                          \
  __builtin_amdgcn_global_load_lds(                                               \
      (const __attribute__((address_space(1))) unsigned int*)(g),                 \
      (__attribute__((address_space(3))) unsigned int*)(l), 16, 0, 0)

// ---------------- fused stats: max|x| (blocks 0..2047), sum|W| (2048..2559) ----
__global__ __launch_bounds__(256) void k_stats(const float4* __restrict__ x,
                                               const float4* __restrict__ w,
                                               unsigned* __restrict__ gx_bits,
                                               double* __restrict__ gw_sum) {
  const int b = blockIdx.x;
  const int lane = threadIdx.x & 63, wv = threadIdx.x >> 6;
  if (b < 2048) {
    const long S = 524288;
    long i = (long)b * 256 + threadIdx.x;
    float m0 = 0.f, m1 = 0.f, m2 = 0.f, m3 = 0.f;
#pragma unroll
    for (int it = 0; it < 4; ++it) {
      float4 v0 = x[i];
      float4 v1 = x[i + S];
      float4 v2 = x[i + 2 * S];
      float4 v3 = x[i + 3 * S];
      m0 = fmaxf(m0, fmaxf(fmaxf(fabsf(v0.x), fabsf(v0.y)), fmaxf(fabsf(v0.z), fabsf(v0.w))));
      m1 = fmaxf(m1, fmaxf(fmaxf(fabsf(v1.x), fabsf(v1.y)), fmaxf(fabsf(v1.z), fabsf(v1.w))));
      m2 = fmaxf(m2, fmaxf(fmaxf(fabsf(v2.x), fabsf(v2.y)), fmaxf(fabsf(v2.z), fabsf(v2.w))));
      m3 = fmaxf(m3, fmaxf(fmaxf(fabsf(v3.x), fabsf(v3.y)), fmaxf(fabsf(v3.z), fabsf(v3.w))));
      i += 4 * S;
    }
    float m = fmaxf(fmaxf(m0, m1), fmaxf(m2, m3));
#pragma unroll
    for (int off = 32; off > 0; off >>= 1) m = fmaxf(m, __shfl_down(m, off));
    __shared__ float sm[4];
    if (lane == 0) sm[wv] = m;
    __syncthreads();
    if (threadIdx.x == 0) {
      float bm = fmaxf(fmaxf(sm[0], sm[1]), fmaxf(sm[2], sm[3]));
      atomicMax(gx_bits, __float_as_uint(bm));  // all >= 0
    }
  } else {
    const long S = 131072;
    long i = (long)(b - 2048) * 256 + threadIdx.x;
    double s = 0.0;
#pragma unroll
    for (int it = 0; it < 8; ++it) {
      float4 v = w[i];
      s += (double)fabsf(v.x) + (double)fabsf(v.y) + (double)fabsf(v.z) + (double)fabsf(v.w);
      i += S;
    }
#pragma unroll
    for (int off = 32; off > 0; off >>= 1) s += __shfl_down(s, off);
    __shared__ double sd[4];
    if (lane == 0) sd[wv] = s;
    __syncthreads();
    if (threadIdx.x == 0) atomicAdd(gw_sum, (sd[0] + sd[1]) + (sd[2] + sd[3]));
  }
}

// ---------------- fused quant: x (blocks 0..2047), W (2048..2559) ----------------
__global__ __launch_bounds__(256) void k_quant(const float4* __restrict__ x,
                                               const float4* __restrict__ w,
                                               char4* __restrict__ xq,
                                               char4* __restrict__ wq,
                                               const unsigned* __restrict__ gx_bits,
                                               const double* __restrict__ gw_sum) {
  const int b = blockIdx.x;
  if (b < 2048) {
    const double gx = (double)fmaxf(__uint_as_float(*gx_bits), 1e-8f);
    const double scale = 127.0 / gx;
    const long S = 524288;
    long i = (long)b * 256 + threadIdx.x;
#pragma unroll
    for (int it = 0; it < 16; ++it) {
      float4 v = x[i];
      char4 o;
      o.x = (signed char)(int)fmin(fmax(rint((double)v.x * scale), -127.0), 127.0);
      o.y = (signed char)(int)fmin(fmax(rint((double)v.y * scale), -127.0), 127.0);
      o.z = (signed char)(int)fmin(fmax(rint((double)v.z * scale), -127.0), 127.0);
      o.w = (signed char)(int)fmin(fmax(rint((double)v.w * scale), -127.0), 127.0);
      xq[i] = o;
      i += S;
    }
  } else {
    const double gw = fmax(*gw_sum * (1.0 / 4194304.0), 1e-8);
    const double inv = 1.0 / gw;
    const long S = 131072;
    long i = (long)(b - 2048) * 256 + threadIdx.x;
#pragma unroll
    for (int it = 0; it < 8; ++it) {
      float4 v = w[i];
      char4 o;
      o.x = (signed char)(int)fmin(fmax(rint((double)v.x * inv), -1.0), 1.0);
      o.y = (signed char)(int)fmin(fmax(rint((double)v.y * inv), -1.0), 1.0);
      o.z = (signed char)(int)fmin(fmax(rint((double)v.z * inv), -1.0), 1.0);
      o.w = (signed char)(int)fmin(fmax(rint((double)v.w * inv), -1.0), 1.0);
      wq[i] = o;
      i += S;
    }
  }
}

// ================= GEMM =================
// LDS layout: A buf0 @0, A buf1 @8192, B buf0 @16384, B buf1 @32768.

template <int BUF>
__device__ __forceinline__ void stageA(signed char* lds, const signed char* gp, int kb,
                                       int goA, int wslotA) {
  constexpr int R = BUF * 8192;
  GLOAD_LDS16(gp + kb + goA, lds + R + wslotA);
  GLOAD_LDS16(gp + kb + goA + 16 * 2048, lds + R + wslotA + 1024);
}

template <int BUF>
__device__ __forceinline__ void stageB(signed char* lds, const signed char* gp, int kb,
                                       int goB, int wslotB) {
  constexpr int R = 16384 + BUF * 16384;
  GLOAD_LDS16(gp + kb + goB, lds + R + wslotB);
  GLOAD_LDS16(gp + kb + goB + 16 * 2048, lds + R + wslotB + 1024);
  GLOAD_LDS16(gp + kb + goB + 32 * 2048, lds + R + wslotB + 2048);
  GLOAD_LDS16(gp + kb + goB + 48 * 2048, lds + R + wslotB + 3072);
}

template <int C>
__device__ __forceinline__ void kstep(signed char* lds, const signed char* Ap,
                                      const signed char* Bp, int kb,
                                      const signed char* pA, const signed char* pB,
                                      int goA, int goB, int wslotA, int wslotB,
                                      i32x4 acc[8][4]) {
  constexpr int RA = C * 8192;
  constexpr int RB = 16384 + C * 16384;
  i32x4 b4[4], a4[4];
  // ---- phase A: lo half of M ----
#pragma unroll
  for (int n = 0; n < 4; ++n) b4[n] = *(const i32x4*)(pB + RB + n * 1024);
#pragma unroll
  for (int m = 0; m < 4; ++m) a4[m] = *(const i32x4*)(pA + RA + m * 1024);
  stageA<C ^ 1>(lds, Ap, kb, goA, wslotA);
  __builtin_amdgcn_s_barrier();
  asm volatile("s_waitcnt lgkmcnt(0)" ::: "memory");
  __builtin_amdgcn_s_setprio(1);
#pragma unroll
  for (int m = 0; m < 4; ++m)
#pragma unroll
    for (int n = 0; n < 4; ++n)
      acc[m][n] = __builtin_amdgcn_mfma_i32_16x16x64_i8(a4[m], b4[n], acc[m][n], 0, 0, 0);
  __builtin_amdgcn_s_setprio(0);
  // ---- phase B: hi half of M ----
#pragma unroll
  for (int m = 0; m < 4; ++m) a4[m] = *(const i32x4*)(pA + RA + 4096 + m * 1024);
  stageB<C ^ 1>(lds, Bp, kb, goB, wslotB);
  __builtin_amdgcn_s_barrier();
  asm volatile("s_waitcnt lgkmcnt(0)" ::: "memory");
  __builtin_amdgcn_s_setprio(1);
#pragma unroll
  for (int m = 0; m < 4; ++m)
#pragma unroll
    for (int n = 0; n < 4; ++n)
      acc[4 + m][n] =
          __builtin_amdgcn_mfma_i32_16x16x64_i8(a4[m], b4[n], acc[4 + m][n], 0, 0, 0);
  __builtin_amdgcn_s_setprio(0);
  asm volatile("s_waitcnt vmcnt(0)" ::: "memory");
  __builtin_amdgcn_s_barrier();  // publish buf C^1; all reads of buf C done
}

__global__ __launch_bounds__(256, 2) void k_gemm(
    const signed char* __restrict__ Aq, const signed char* __restrict__ Bq,
    const float* __restrict__ bias, float* __restrict__ out,
    const unsigned* __restrict__ gx_bits, const double* __restrict__ gw_sum) {
  extern __shared__ signed char lds[];

  const int tid = threadIdx.x;
  const int lane = tid & 63;
  const int wid = tid >> 6;       // 0..3 = wave_n
  const int l15 = lane & 15;

  // XCD swizzle: nwg = 1024, 8 XCDs, 128 contiguous work-ids per XCD;
  // 8 consecutive wg share one A-tile (all nblk values) -> A L2 reuse.
  const int wg = (int)((blockIdx.x & 7) * 128 + (blockIdx.x >> 3));
  const int nblk = wg & 7;   // N_/256 = 8
  const int mblk = wg >> 3;  // 0..127
  const long brow = (long)mblk * 128;
  const long bcol = (long)nblk * 256;

  const signed char* Ap = Aq + brow * K_;
  const signed char* Bp = Bq + bcol * K_;

  // LDS read bases; all row bases are multiples of 16 -> swizzle term
  // depends only on lane&15
  const int swz = ((lane >> 4) ^ ((l15 >> 1) & 3)) << 4;
  const signed char* pA = lds + l15 * 64 + swz;
  const signed char* pB = lds + (wid * 64 + l15) * 64 + swz;

  // stage offsets (global chunk pre-swizzled: c0 = (lane&3)^((lane>>3)&3))
  const int c0 = (lane & 3) ^ ((lane >> 3) & 3);
  const int goA = (wid * 32 + (lane >> 2)) * (int)K_ + c0 * 16;
  const int goB = (wid * 64 + (lane >> 2)) * (int)K_ + c0 * 16;
  const int wslotA = wid * 2048;
  const int wslotB = wid * 4096;

  i32x4 acc[8][4];
#pragma unroll
  for (int m = 0; m < 8; m++)
#pragma unroll
    for (int n = 0; n < 4; n++) acc[m][n] = (i32x4){0, 0, 0, 0};

  // prologue: stage K-step 0 into buf0
  stageA<0>(lds, Ap, 0, goA, wslotA);
  stageB<0>(lds, Bp, 0, goB, wslotB);
  asm volatile("s_waitcnt vmcnt(0)" ::: "memory");
  __builtin_amdgcn_s_barrier();

  for (int kt = 0; kt < (int)K_; kt += 128) {
    const int kb0 = kt + 64;             // staged during step kt (c=0)
    const int kb1 = (kt + 128) & 2047;   // staged during step kt+64 (c=1)
    kstep<0>(lds, Ap, Bp, kb0, pA, pB, goA, goB, wslotA, wslotB, acc);
    kstep<1>(lds, Ap, Bp, kb1, pA, pB, goA, goB, wslotA, wslotB, acc);
  }

  const float gxf = fmaxf(__uint_as_float(*gx_bits), 1e-8f);
  const double gwd = fmax(*gw_sum * (1.0 / 4194304.0), 1e-8);
  const float alpha = (float)((double)gxf * gwd * (1.0 / 127.0));

#pragma unroll
  for (int n = 0; n < 4; ++n) {
    const long col = bcol + wid * 64 + n * 16 + l15;
    const float bv = bias[col];
#pragma unroll
    for (int m = 0; m < 8; ++m) {
      const long row0 = brow + m * 16 + (lane >> 4) * 4;
#pragma unroll
      for (int r = 0; r < 4; ++r) {
        out[(row0 + r) * N_ + col] = (float)acc[m][n][r] * alpha + bv;
      }
    }
  }
}

extern "C" void kernel_launch(void* const* d_in, const int* in_sizes, int n_in,
                              void* d_out, int out_size, void* d_ws, size_t ws_size,
                              hipStream_t stream) {
  const float* x = (const float*)d_in[0];
  const float* W = (const float*)d_in[1];
  const float* b = (const float*)d_in[2];
  float* out = (float*)d_out;

  char* ws = (char*)d_ws;
  double* gw_sum = (double*)ws;            // 8 B
  unsigned* gx_bits = (unsigned*)(ws + 8); // 4 B
  signed char* xq = (signed char*)(ws + 256);                            // M*K i8 = 32 MiB
  signed char* wq = (signed char*)(ws + 256 + (size_t)M_ * (size_t)K_);  // N*K i8 = 4 MiB

  hipMemsetAsync(ws, 0, 16, stream);
  hipLaunchKernelGGL(k_stats, dim3(2560), dim3(256), 0, stream,
                     (const float4*)x, (const float4*)W, gx_bits, gw_sum);
  hipLaunchKernelGGL(k_quant, dim3(2560), dim3(256), 0, stream,
                     (const float4*)x, (const float4*)W, (char4*)xq, (char4*)wq,
                     gx_bits, gw_sum);
  hipLaunchKernelGGL(k_gemm, dim3((unsigned)((M_ / 128) * (N_ / 256))), dim3(256),
                     49152, stream, xq, wq, b, out, gx_bits, gw_sum);
}